// Round 8
// baseline (299.158 us; speedup 1.0000x reference)
//
#include <hip/hip_runtime.h>
#include <cstdint>
#include <cstddef>

#define NN 20000   // nodes
#define NE 320000  // edges
#define D  128     // embed dim
#define TW 8       // towers
#define FT 16      // per-tower features
#define NL 3       // layers
#define NS 4096    // subgraphs
#define INR 512    // (L+1)*D

typedef unsigned short u16;
typedef __attribute__((ext_vector_type(8))) short short8;
typedef __attribute__((ext_vector_type(4))) float f32x4;

__device__ __forceinline__ float b2f(short s) {
    return __uint_as_float(((unsigned)(u16)s) << 16);
}
__device__ __forceinline__ u16 f2b(float f) {
    unsigned u = __float_as_uint(f);
    return (u16)((u + 0x7FFF + ((u >> 16) & 1)) >> 16);   // RNE
}

// ---------------- scan (block 0: deg->eoff over NN, block 1: scnt->soff over NS) ----

__global__ void scan2_kernel(const int* __restrict__ cnt0, int* __restrict__ off0,
                             const int* __restrict__ cnt1, int* __restrict__ off1) {
    __shared__ int lds[1024];
    const int tid = threadIdx.x;
    const int* cnt = blockIdx.x ? cnt1 : cnt0;
    int*       off = blockIdx.x ? off1 : off0;
    const int n   = blockIdx.x ? NS : NN;
    const int per = (n + 1023) >> 10;
    const int s = tid * per;
    const int e = min(s + per, n);
    int sum = 0;
    for (int i = s; i < e; ++i) sum += cnt[i];
    lds[tid] = sum;
    __syncthreads();
    for (int o = 1; o < 1024; o <<= 1) {
        int v = (tid >= o) ? lds[tid - o] : 0;
        __syncthreads();
        if (tid >= o) lds[tid] += v;
        __syncthreads();
    }
    int base = (tid == 0) ? 0 : lds[tid - 1];
    for (int i = s; i < e; ++i) { off[i] = base; base += cnt[i]; }
    if (tid == 1023) off[n] = lds[1023];
}

__global__ void fill_kernel(const int* __restrict__ ei, const int* __restrict__ sub,
                            const int* __restrict__ eoff, int* __restrict__ ecur,
                            int* __restrict__ csr,
                            const int* __restrict__ soff, int* __restrict__ scur,
                            int* __restrict__ snodes) {
    int i = blockIdx.x * blockDim.x + threadIdx.x;
    if (i < NE) {
        int dd = ei[NE + i];
        int p = atomicAdd(&ecur[dd], 1);
        csr[eoff[dd] + p] = ei[i];          // src
    }
    if (i < NN) {
        int g = sub[i];
        int p = atomicAdd(&scur[g], 1);
        snodes[soff[g] + p] = i;
    }
}

// ---------------- merged prep ----------------
// blocks: 0..23 tower-fold | 24..279 weff | 280..311 beff | 312..335 packB
//         | 336..1585 x->bf16 | 1586..2835 count (deg/scnt atomics)
__global__ __launch_bounds__(256)
void prep_kernel(const float* __restrict__ pre_w, const float* __restrict__ pre_b,
                 const float* __restrict__ post_w,
                 float* __restrict__ cw, float* __restrict__ cv,
                 const float* __restrict__ op_w, const float* __restrict__ op_b,
                 const float* __restrict__ gma, const float* __restrict__ bta,
                 const float* __restrict__ mean, const float* __restrict__ var,
                 float* __restrict__ wefft, float* __restrict__ beff,
                 const float* __restrict__ lin_w, u16* __restrict__ packB,
                 const float* __restrict__ x, u16* __restrict__ xbf,
                 const int* __restrict__ ei, const int* __restrict__ sub,
                 int* __restrict__ deg, int* __restrict__ scnt) {
    const int b = blockIdx.x;
    const int tid = threadIdx.x;
    if (b < 24) {                          // ---- tower fold (fp32)
        const int lt = b;
        const int dd = tid >> 4;
        const int ff = tid & 15;
        const float* PW = pre_w  + (size_t)lt * (FT * 2 * FT);
        const float* QW = post_w + (size_t)lt * (FT * 2 * FT);
        const float* PB = pre_b  + (size_t)lt * FT;
        float m1 = QW[dd * 32 + ff];
        float m2 = 0.f, m3 = 0.f, v = 0.f;
        for (int k = 0; k < FT; ++k) {
            float pb = QW[dd * 32 + 16 + k];
            m2 = fmaf(pb, PW[k * 32 + ff], m2);
            m3 = fmaf(pb, PW[k * 32 + 16 + ff], m3);
            if (ff == 0) v = fmaf(pb, PB[k], v);
        }
        float* o = cw + ((size_t)lt * 16 + dd) * 48;
        o[ff] = m1; o[16 + ff] = m2; o[32 + ff] = m3;
        if (ff == 0) cv[lt * 16 + dd] = v;
    } else if (b < 280) {                  // ---- wefft[j][d] = op_w[d][j]*scale[j]
        int i = (b - 24) * 256 + tid;
        int j = i >> 7, d = i & (D - 1);
        float sc = gma[j] * rsqrtf(var[j] + 1e-5f);
        wefft[(size_t)j * D + d] = op_w[(size_t)d * INR + j] * sc;
    } else if (b < 312) {                  // ---- beff rows (4/block)
        const int d = (b - 280) * 4 + (tid >> 6);
        const int lane = tid & 63;
        float acc = 0.f;
        for (int j = lane; j < INR; j += 64) {
            float sc = gma[j] * rsqrtf(var[j] + 1e-5f);
            float sh = bta[j] - mean[j] * sc;
            acc = fmaf(op_w[(size_t)d * INR + j], sh, acc);
        }
#pragma unroll
        for (int o = 32; o; o >>= 1) acc += __shfl_down(acc, o);
        if (lane == 0) beff[d] = acc + op_b[d];
    } else if (b < 336) {                  // ---- pack lin_w into per-lane MFMA B-frags
        const int lt = b - 312;            // l*8 + ct
        const int l  = lt >> 3, ct = lt & 7;
        const int ks = tid >> 6;           // 0..3
        const int lane = tid & 63;
        const int col = ct * 16 + (lane & 15);
        const int k0  = ks * 32 + ((lane >> 4) & 3) * 8;
        const float* lw = lin_w + (size_t)l * D * D + (size_t)col * D + k0;
        u16* o = packB + ((size_t)(lt * 4 + ks) * 64 + lane) * 8;
#pragma unroll
        for (int j = 0; j < 8; ++j) o[j] = f2b(lw[j]);
    } else if (b < 1586) {                 // ---- x -> bf16 copy (2048 elems/block)
        const size_t base = (size_t)(b - 336) * 2048 + (size_t)tid * 8;
        float4 a = *(const float4*)(x + base);
        float4 c = *(const float4*)(x + base + 4);
        u16 o[8] = { f2b(a.x), f2b(a.y), f2b(a.z), f2b(a.w),
                     f2b(c.x), f2b(c.y), f2b(c.z), f2b(c.w) };
        uint4 u;
        u.x = (unsigned)o[0] | ((unsigned)o[1] << 16);
        u.y = (unsigned)o[2] | ((unsigned)o[3] << 16);
        u.z = (unsigned)o[4] | ((unsigned)o[5] << 16);
        u.w = (unsigned)o[6] | ((unsigned)o[7] << 16);
        *(uint4*)(xbf + base) = u;
    } else {                               // ---- count (deg / scnt atomics)
        int i = (b - 1586) * 256 + tid;
        if (i < NE) atomicAdd(&deg[ei[NE + i]], 1);
        if (i < NN) atomicAdd(&scnt[sub[i]], 1);
    }
}

// ---------------- fused gather + PNA update ----------------
// 1 block = 16 nodes, 512 threads (8 waves).
// Phase G: wave w gathers nodes 2w,2w+1 (neighbor-sum -> SG fp32; x-row -> XL bf16).
// Phase T: fp32 tower from LDS. Phase M: bf16 MFMA matvec vs prepacked lin fragments.
__global__ __launch_bounds__(512, 4)
void fgu_kernel(const u16* __restrict__ hin, const int* __restrict__ eoff,
                const int* __restrict__ csr, const int* __restrict__ deg,
                const float* __restrict__ cw, const float* __restrict__ cv,
                const float* __restrict__ post_b, const u16* __restrict__ packB,
                const float* __restrict__ lin_b, u16* __restrict__ hout, int l) {
    __shared__ float SG[16 * 128];     // gathered neighbor sums (8 KB)
    __shared__ u16   XL[16 * 128];     // staged x rows (4 KB)
    __shared__ u16   OBS[16 * 136];    // tower output, padded stride (4.25 KB)
    __shared__ float DG[16];

    const int tid  = threadIdx.x;
    const int lane = tid & 63;
    const int wv   = tid >> 6;         // 0..7
    const int n0   = blockIdx.x << 4;

    // MFMA B-fragments for this wave's column tile
    short8 BF[4];
    {
        const short8* pB = (const short8*)packB + (size_t)((l * 8 + wv) * 4) * 64 + lane;
#pragma unroll
        for (int ks = 0; ks < 4; ++ks) BF[ks] = pB[ks * 64];
    }
    const float bl = lin_b[l * D + wv * 16 + (lane & 15)];

    // ---- Phase G: gather 2 nodes per wave
    {
        const int half = lane >> 5;
        const int q    = lane & 31;
#pragma unroll
        for (int u = 0; u < 2; ++u) {
            const int ln = wv * 2 + u;
            const int node = n0 + ln;
            // stage x row: 64 lanes x 4B = 256 B
            ((unsigned*)XL)[ln * 64 + lane] =
                ((const unsigned*)(hin + (size_t)node * D))[lane];
            if (lane == 0) DG[ln] = (float)deg[node];
            const int e0 = eoff[node], e1 = eoff[node + 1];
            const uint2* h2 = (const uint2*)hin;
            float ax = 0.f, ay = 0.f, az = 0.f, aw = 0.f;
            int e = e0;
            for (; e + 8 <= e1; e += 8) {
#pragma unroll
                for (int k = 0; k < 4; ++k) {
                    int s = csr[e + 2 * k + half];
                    uint2 v = h2[(size_t)s * 32 + q];
                    ax += __uint_as_float(v.x << 16);
                    ay += __uint_as_float(v.x & 0xFFFF0000u);
                    az += __uint_as_float(v.y << 16);
                    aw += __uint_as_float(v.y & 0xFFFF0000u);
                }
            }
            for (; e < e1; e += 2) {
                int idx = e + half;
                bool valid = idx < e1;
                int s = valid ? csr[idx] : 0;
                uint2 v = h2[(size_t)s * 32 + q];
                if (valid) {
                    ax += __uint_as_float(v.x << 16);
                    ay += __uint_as_float(v.x & 0xFFFF0000u);
                    az += __uint_as_float(v.y << 16);
                    aw += __uint_as_float(v.y & 0xFFFF0000u);
                }
            }
            ax += __shfl_xor(ax, 32);
            ay += __shfl_xor(ay, 32);
            az += __shfl_xor(az, 32);
            aw += __shfl_xor(aw, 32);
            if (half == 0) {
                float4 r; r.x = ax; r.y = ay; r.z = az; r.w = aw;
                ((float4*)SG)[ln * 32 + q] = r;
            }
        }
    }
    __syncthreads();

    // ---- Phase T: fp32 tower, 4 nodes per thread (si group), all operands in LDS
    {
        const int si  = tid >> 7;      // 0..3
        const int d   = tid & 127;
        const int t16 = d & ~15;
        const int dd  = d & 15;
        const float* wb = cw + ((size_t)(l * TW + (d >> 4)) * 16 + dd) * 48;
        const float4* wb4 = (const float4*)wb;
        float m1[16], m2[16], m3[16];
#pragma unroll
        for (int qq = 0; qq < 4; ++qq) {
            float4 t1 = wb4[qq], t2 = wb4[4 + qq], t3 = wb4[8 + qq];
            m1[qq*4+0]=t1.x; m1[qq*4+1]=t1.y; m1[qq*4+2]=t1.z; m1[qq*4+3]=t1.w;
            m2[qq*4+0]=t2.x; m2[qq*4+1]=t2.y; m2[qq*4+2]=t2.z; m2[qq*4+3]=t2.w;
            m3[qq*4+0]=t3.x; m3[qq*4+1]=t3.y; m3[qq*4+2]=t3.z; m3[qq*4+3]=t3.w;
        }
        const float vq = cv[(l * TW + (d >> 4)) * 16 + dd];
        const float cb = post_b[l * D + d];
#pragma unroll
        for (int u = 0; u < 4; ++u) {
            const int ln = si * 4 + u;
            const short8* hp = (const short8*)&XL[ln * 128 + t16];
            short8 hx0 = hp[0], hx1 = hp[1];
            const float4* sp = (const float4*)&SG[ln * 128 + t16];
            float4 sv0 = sp[0], sv1 = sp[1], sv2 = sp[2], sv3 = sp[3];
            float ax = 0.f, am = 0.f, as2 = 0.f;
#pragma unroll
            for (int j = 0; j < 8; ++j) {
                float xf = b2f(hx0[j]);
                ax = fmaf(m1[j], xf, ax);
                am = fmaf(m2[j], xf, am);
            }
#pragma unroll
            for (int j = 0; j < 8; ++j) {
                float xf = b2f(hx1[j]);
                ax = fmaf(m1[8 + j], xf, ax);
                am = fmaf(m2[8 + j], xf, am);
            }
            as2 = fmaf(m3[0], sv0.x, as2); as2 = fmaf(m3[1], sv0.y, as2);
            as2 = fmaf(m3[2], sv0.z, as2); as2 = fmaf(m3[3], sv0.w, as2);
            as2 = fmaf(m3[4], sv1.x, as2); as2 = fmaf(m3[5], sv1.y, as2);
            as2 = fmaf(m3[6], sv1.z, as2); as2 = fmaf(m3[7], sv1.w, as2);
            as2 = fmaf(m3[8], sv2.x, as2); as2 = fmaf(m3[9], sv2.y, as2);
            as2 = fmaf(m3[10], sv2.z, as2); as2 = fmaf(m3[11], sv2.w, as2);
            as2 = fmaf(m3[12], sv3.x, as2); as2 = fmaf(m3[13], sv3.y, as2);
            as2 = fmaf(m3[14], sv3.z, as2); as2 = fmaf(m3[15], sv3.w, as2);
            OBS[ln * 136 + d] = f2b(cb + ax + as2 + DG[ln] * (am + vq));
        }
    }
    __syncthreads();

    // ---- Phase M: MFMA matvec, wave wv computes OUT[0:16][wv*16 : +16]
    f32x4 c = {0.f, 0.f, 0.f, 0.f};
#pragma unroll
    for (int ks = 0; ks < 4; ++ks) {
        const short8 a = *(const short8*)((const char*)OBS +
                            (lane & 15) * 272 + (ks * 4 + (lane >> 4)) * 16);
        c = __builtin_amdgcn_mfma_f32_16x16x32_bf16(a, BF[ks], c, 0, 0, 0);
    }
    const int d_epi = wv * 16 + (lane & 15);
#pragma unroll
    for (int r = 0; r < 4; ++r) {
        const int node = n0 + (lane >> 4) * 4 + r;   // C: col=lane&15, row=(lane>>4)*4+r
        float v = fmaxf(c[r] + bl, 0.f);
        hout[(size_t)node * D + d_epi] = f2b(v);
    }
}

// ---------------- fused pooling + BN + out GEMM ----------------
// 16 subgraphs/block, 512 threads = 4 segs/j-quarters x 128 d
__global__ __launch_bounds__(512)
void pool_out_kernel(const u16* __restrict__ h0, const u16* __restrict__ h1,
                     const u16* __restrict__ h2, const u16* __restrict__ h3,
                     const int* __restrict__ soff, const int* __restrict__ snodes,
                     const float* __restrict__ wefft, const float* __restrict__ beff,
                     float* __restrict__ out) {
    __shared__ float sm[16 * INR];   // 32 KB; pooled rows, then partials
    const int tid = threadIdx.x;
    const int q = tid >> 7;
    const int d = tid & 127;
    const int s0 = blockIdx.x * 16;
    const u16* hq = (q == 0) ? h0 : (q == 1) ? h1 : (q == 2) ? h2 : h3;
    // ---- pool: thread (q,d) accumulates column q*128+d for 16 subgraphs
    for (int i = 0; i < 16; ++i) {
        const int a0 = soff[s0 + i], a1 = soff[s0 + i + 1];
        float acc = 0.f;
        for (int a = a0; a < a1; ++a) {
            int n = snodes[a];
            acc += b2f(hq[(size_t)n * D + d]);
        }
        sm[i * INR + q * 128 + d] = acc;
    }
    __syncthreads();
    // ---- GEMM: 4 j-quarters x 128 d
    float acc[16];
#pragma unroll
    for (int i = 0; i < 16; ++i) acc[i] = 0.f;
    for (int jj4 = 0; jj4 < 32; ++jj4) {
        const int j0 = q * 128 + jj4 * 4;
        float wv0 = wefft[(size_t)(j0 + 0) * D + d];
        float wv1 = wefft[(size_t)(j0 + 1) * D + d];
        float wv2 = wefft[(size_t)(j0 + 2) * D + d];
        float wv3 = wefft[(size_t)(j0 + 3) * D + d];
#pragma unroll
        for (int i = 0; i < 16; ++i) {
            float4 pv = *(const float4*)&sm[i * INR + j0];
            acc[i] = fmaf(pv.x, wv0, acc[i]);
            acc[i] = fmaf(pv.y, wv1, acc[i]);
            acc[i] = fmaf(pv.z, wv2, acc[i]);
            acc[i] = fmaf(pv.w, wv3, acc[i]);
        }
    }
    __syncthreads();
#pragma unroll
    for (int i = 0; i < 16; ++i) sm[(q * 16 + i) * 128 + d] = acc[i];
    __syncthreads();
    const float bb = beff[d];
#pragma unroll
    for (int ii = 0; ii < 4; ++ii) {
        int i = q * 4 + ii;
        float v = sm[i * 128 + d] + sm[(16 + i) * 128 + d]
                + sm[(32 + i) * 128 + d] + sm[(48 + i) * 128 + d];
        out[(size_t)(s0 + i) * D + d] = v + bb;
    }
}

// ---------------- launch ----------------

extern "C" void kernel_launch(void* const* d_in, const int* in_sizes, int n_in,
                              void* d_out, int out_size, void* d_ws, size_t ws_size,
                              hipStream_t stream) {
    const float* x      = (const float*)d_in[0];
    const int*   ei     = (const int*)d_in[1];
    const int*   sub    = (const int*)d_in[2];
    const float* pre_w  = (const float*)d_in[3];
    const float* pre_b  = (const float*)d_in[4];
    const float* post_w = (const float*)d_in[5];
    const float* post_b = (const float*)d_in[6];
    const float* lin_w  = (const float*)d_in[7];
    const float* lin_b  = (const float*)d_in[8];
    const float* bn_g   = (const float*)d_in[9];
    const float* bn_b   = (const float*)d_in[10];
    const float* bn_m   = (const float*)d_in[11];
    const float* bn_v   = (const float*)d_in[12];
    const float* op_w   = (const float*)d_in[13];
    const float* op_b   = (const float*)d_in[14];
    float* out = (float*)d_out;

    char* p = (char*)d_ws;
    auto alloc = [&](size_t bytes) -> char* {
        char* q = p;
        p += (bytes + 255) & ~(size_t)255;
        return q;
    };

    char* zero_start = p;
    int* deg  = (int*)alloc(sizeof(int) * NN);
    int* ecur = (int*)alloc(sizeof(int) * NN);
    int* scnt = (int*)alloc(sizeof(int) * NS);
    int* scur = (int*)alloc(sizeof(int) * NS);
    size_t zero_span = (size_t)(p - zero_start);

    int* eoff   = (int*)alloc(sizeof(int) * (NN + 1));
    int* soff   = (int*)alloc(sizeof(int) * (NS + 1));
    int* csr    = (int*)alloc(sizeof(int) * NE);
    int* snodes = (int*)alloc(sizeof(int) * NN);
    u16* xbf    = (u16*)alloc(sizeof(u16) * (size_t)NN * D);
    u16* h1     = (u16*)alloc(sizeof(u16) * (size_t)NN * D);
    u16* h2     = (u16*)alloc(sizeof(u16) * (size_t)NN * D);
    u16* h3     = (u16*)alloc(sizeof(u16) * (size_t)NN * D);
    float* wefft  = (float*)alloc(sizeof(float) * (size_t)INR * D);
    float* beff   = (float*)alloc(sizeof(float) * D);
    float* cw     = (float*)alloc(sizeof(float) * NL * TW * 16 * 48);
    float* cv     = (float*)alloc(sizeof(float) * NL * TW * 16);
    u16* packB    = (u16*)alloc(sizeof(u16) * NL * 8 * 4 * 64 * 8);

    hipMemsetAsync(zero_start, 0, zero_span, stream);

    prep_kernel<<<2836, 256, 0, stream>>>(pre_w, pre_b, post_w, cw, cv,
                                          op_w, op_b, bn_g, bn_b, bn_m, bn_v,
                                          wefft, beff, lin_w, packB, x, xbf,
                                          ei, sub, deg, scnt);
    scan2_kernel<<<2, 1024, 0, stream>>>(deg, eoff, scnt, soff);
    fill_kernel<<<(NE + 255) / 256, 256, 0, stream>>>(ei, sub, eoff, ecur, csr,
                                                      soff, scur, snodes);

    const u16* hs[4] = { xbf, h1, h2, h3 };
    for (int l = 0; l < NL; ++l) {
        fgu_kernel<<<NN / 16, 512, 0, stream>>>(hs[l], eoff, csr, deg, cw, cv,
                                                post_b, packB, lin_b,
                                                (u16*)hs[l + 1], l);
    }

    pool_out_kernel<<<NS / 16, 512, 0, stream>>>(xbf, h1, h2, h3, soff, snodes,
                                                 wefft, beff, out);
}